// Round 1
// baseline (389.090 us; speedup 1.0000x reference)
//
#include <hip/hip_runtime.h>
#include <stdint.h>

#define B_SZ    2
#define L_SEQ   2048
#define DMODEL  768
#define DSTATE  16
#define DINNER  1536
#define DTRANK  48
#define M_ROWS  4096      // B*L
#define NCHUNK  32
#define TCHUNK  64

typedef __attribute__((ext_vector_type(8))) short bf16x8;
typedef __attribute__((ext_vector_type(4))) float f32x4;
typedef __attribute__((ext_vector_type(4))) unsigned int u32x4;

__device__ __forceinline__ unsigned short f2bf(float f) {
  unsigned int u = __float_as_uint(f);
  u += 0x7FFFu + ((u >> 16) & 1u);          // RNE
  return (unsigned short)(u >> 16);
}
__device__ __forceinline__ float bf2f(unsigned short h) {
  return __uint_as_float(((unsigned int)h) << 16);
}
__device__ __forceinline__ float fexp(float x) {   // e^x via v_exp_f32
  return __builtin_amdgcn_exp2f(x * 1.44269504088896340736f);
}
__device__ __forceinline__ float sigm(float x) {
  return 1.0f / (1.0f + fexp(-x));
}

// ---------------------------------------------------------------- casts ----
__global__ void cast_all_kernel(const float* __restrict__ x, const float* __restrict__ w1,
                                const float* __restrict__ w2, const float* __restrict__ w3,
                                const float* __restrict__ dtw,
                                unsigned short* __restrict__ xbf, unsigned short* __restrict__ w1bf,
                                unsigned short* __restrict__ w2bf, unsigned short* __restrict__ w3bf,
                                unsigned short* __restrict__ dtwbf) {
  int i = blockIdx.x * 256 + threadIdx.x;
  const int n_x = M_ROWS * DMODEL;          // 3145728
  const int n_w1 = 2 * DINNER * DMODEL;     // 2359296
  const int n_w3 = DMODEL * DINNER;         // 1179648
  const int n_w2 = 128 * DINNER;            // 196608 (rows padded 80->128)
  const int n_dtw = DINNER * 64;            // 98304  (cols padded 48->64)
  if (i < n_x)  { xbf[i] = f2bf(x[i]); return; }  i -= n_x;
  if (i < n_w1) { w1bf[i] = f2bf(w1[i]); return; } i -= n_w1;
  if (i < n_w3) { w3bf[i] = f2bf(w3[i]); return; } i -= n_w3;
  if (i < n_w2) {
    int row = i / DINNER, col = i - row * DINNER;
    w2bf[i] = (row < (DTRANK + 2 * DSTATE)) ? f2bf(w2[row * DINNER + col]) : (unsigned short)0;
    return;
  }
  i -= n_w2;
  if (i < n_dtw) {
    int row = i >> 6, col = i & 63;
    dtwbf[i] = (col < DTRANK) ? f2bf(dtw[row * DTRANK + col]) : (unsigned short)0;
  }
}

__global__ void cast_dtlow_kernel(const float* __restrict__ xdbl, unsigned short* __restrict__ out) {
  int i = blockIdx.x * 256 + threadIdx.x;   // 4096*64
  int row = i >> 6, col = i & 63;
  out[i] = (col < DTRANK) ? f2bf(xdbl[row * 128 + col]) : (unsigned short)0;
}

// --------------------------------------------------- bf16 MFMA GEMM (B^T) ----
// C[m][n] = sum_k A[m][k] * Bt[n][k].  BM=BN=128, BK=32, 256 thr = 4 waves 2x2,
// each wave 64x64 via 4x4 grid of 16x16x32 MFMA. LDS rows padded 32->40 elems
// (80B stride, 16B aligned, 2-way bank pattern = free).
// EPI: 0 = plain f32 store; 1 = softplus(acc + bias[col]).
template <int EPI>
__global__ __launch_bounds__(256, 2) void gemm_bt(
    const unsigned short* __restrict__ A, const unsigned short* __restrict__ Bt,
    float* __restrict__ C, int K, int ldc, const float* __restrict__ bias) {
  __shared__ unsigned short As[128 * 40];
  __shared__ unsigned short Bs[128 * 40];
  const int tid = threadIdx.x;
  const int m0 = blockIdx.x * 128;
  const int n0 = blockIdx.y * 128;
  const int lane = tid & 63;
  const int wave = tid >> 6;
  const int wr = (wave >> 1) * 64, wc = (wave & 1) * 64;
  const int lm = lane & 15, q = lane >> 4;
  const int r = tid >> 2, sg = (tid & 3) * 8;       // staging: row, k-seg(elems)

  f32x4 acc[4][4] = {};

  for (int k0 = 0; k0 < K; k0 += 32) {
    u32x4 a0 = *(const u32x4*)(A + (size_t)(m0 + r) * K + k0 + sg);
    u32x4 a1 = *(const u32x4*)(A + (size_t)(m0 + r + 64) * K + k0 + sg);
    u32x4 b0 = *(const u32x4*)(Bt + (size_t)(n0 + r) * K + k0 + sg);
    u32x4 b1 = *(const u32x4*)(Bt + (size_t)(n0 + r + 64) * K + k0 + sg);
    __syncthreads();
    *(u32x4*)&As[r * 40 + sg] = a0;
    *(u32x4*)&As[(r + 64) * 40 + sg] = a1;
    *(u32x4*)&Bs[r * 40 + sg] = b0;
    *(u32x4*)&Bs[(r + 64) * 40 + sg] = b1;
    __syncthreads();
    bf16x8 af[4], bq[4];
#pragma unroll
    for (int mt = 0; mt < 4; mt++)
      af[mt] = *(const bf16x8*)&As[(wr + mt * 16 + lm) * 40 + q * 8];
#pragma unroll
    for (int nt = 0; nt < 4; nt++)
      bq[nt] = *(const bf16x8*)&Bs[(wc + nt * 16 + lm) * 40 + q * 8];
#pragma unroll
    for (int mt = 0; mt < 4; mt++)
#pragma unroll
      for (int nt = 0; nt < 4; nt++)
        acc[mt][nt] = __builtin_amdgcn_mfma_f32_16x16x32_bf16(af[mt], bq[nt], acc[mt][nt], 0, 0, 0);
  }

#pragma unroll
  for (int mt = 0; mt < 4; mt++) {
    int row0 = m0 + wr + mt * 16 + q * 4;
#pragma unroll
    for (int nt = 0; nt < 4; nt++) {
      int col = n0 + wc + nt * 16 + lm;
      float bs = 0.f;
      if (EPI == 1) bs = bias[col];
#pragma unroll
      for (int i = 0; i < 4; i++) {
        float v = acc[mt][nt][i];
        if (EPI == 1) {                      // softplus(v + b), stable
          v += bs;
          v = (v > 15.f) ? v : log1pf(fexp(v));
        }
        C[(size_t)(row0 + i) * ldc + col] = v;
      }
    }
  }
}

// ------------------------------------------------- depthwise conv + SiLU ----
__global__ void conv_silu_kernel(const float* __restrict__ xz, const float* __restrict__ cw,
                                 const float* __restrict__ cb, unsigned short* __restrict__ xcbf) {
  int idx = blockIdx.x * 256 + threadIdx.x;
  if (idx >= B_SZ * L_SEQ * DINNER) return;
  int d = idx % DINNER;
  int bl = idx / DINNER;          // b*L + l
  int l = bl & (L_SEQ - 1);
  float acc = cb[d];
#pragma unroll
  for (int k = 0; k < 4; k++) {
    int ll = l - 3 + k;
    if (ll >= 0) acc += cw[d * 4 + k] * xz[(size_t)(bl - 3 + k) * 3072 + d];
  }
  xcbf[idx] = f2bf(acc * sigm(acc));
}

// ------------------------------------------------------ chunked SSM scan ----
// lane: s = tid&15, dl = tid>>4 (16 channels per block); chunk of 64 steps.
__global__ __launch_bounds__(256) void scan_phase1(
    const float* __restrict__ dt, const unsigned short* __restrict__ xcbf,
    const float* __restrict__ xdbl, const float* __restrict__ A_log,
    float* __restrict__ P, float* __restrict__ HL) {
  __shared__ float dts[TCHUNK][16], xcs[TCHUNK][16], Bsh[TCHUNK][16];
  const int tid = threadIdx.x;
  const int db = blockIdx.x * 16;
  const int b = blockIdx.y;
  const int c = blockIdx.z;
  const int l0 = c * TCHUNK;
#pragma unroll
  for (int i = 0; i < 4; i++) {
    int idx = tid + i * 256;
    int li = idx >> 4, di = idx & 15;
    size_t row = (size_t)(b * L_SEQ + l0 + li);
    dts[li][di] = dt[row * DINNER + db + di];
    xcs[li][di] = bf2f(xcbf[row * DINNER + db + di]);
    Bsh[li][di] = xdbl[row * 128 + DTRANK + di];
  }
  __syncthreads();
  const int s = tid & 15, dl = tid >> 4;
  const int d = db + dl;
  const float a2 = -fexp(A_log[d * 16 + s]) * 1.44269504f;  // A*log2(e)
  float h = 0.f, p = 1.f;
#pragma unroll 4
  for (int l = 0; l < TCHUNK; l++) {
    float dtv = dts[l][dl];
    float a = __builtin_amdgcn_exp2f(dtv * a2);
    h = a * h + dtv * xcs[l][dl] * Bsh[l][s];
    p *= a;
  }
  size_t o = ((size_t)(c * B_SZ + b) * DINNER + d) * 16 + s;
  P[o] = p;
  HL[o] = h;
}

__global__ void scan_phase2(const float* __restrict__ P, const float* __restrict__ HL,
                            float* __restrict__ HIN) {
  int tg = blockIdx.x * 256 + threadIdx.x;  // 49152 total
  int s = tg & 15;
  int rem = tg >> 4;
  int d = rem % DINNER;
  int b = rem / DINNER;
  float h = 0.f;
  for (int c = 0; c < NCHUNK; c++) {
    size_t o = ((size_t)(c * B_SZ + b) * DINNER + d) * 16 + s;
    HIN[o] = h;
    h = P[o] * h + HL[o];
  }
}

__global__ __launch_bounds__(256) void scan_phase3(
    const float* __restrict__ dt, const unsigned short* __restrict__ xcbf,
    const float* __restrict__ xdbl, const float* __restrict__ A_log,
    const float* __restrict__ HIN, const float* __restrict__ xz,
    const float* __restrict__ Dp, unsigned short* __restrict__ ybf) {
  __shared__ float dts[TCHUNK][16], xcs[TCHUNK][16], Bsh[TCHUNK][16], Csh[TCHUNK][16], ys[TCHUNK][16];
  const int tid = threadIdx.x;
  const int db = blockIdx.x * 16;
  const int b = blockIdx.y;
  const int c = blockIdx.z;
  const int l0 = c * TCHUNK;
#pragma unroll
  for (int i = 0; i < 4; i++) {
    int idx = tid + i * 256;
    int li = idx >> 4, di = idx & 15;
    size_t row = (size_t)(b * L_SEQ + l0 + li);
    dts[li][di] = dt[row * DINNER + db + di];
    xcs[li][di] = bf2f(xcbf[row * DINNER + db + di]);
    Bsh[li][di] = xdbl[row * 128 + DTRANK + di];
    Csh[li][di] = xdbl[row * 128 + DTRANK + DSTATE + di];
  }
  __syncthreads();
  const int s = tid & 15, dl = tid >> 4;
  const int d = db + dl;
  const float a2 = -fexp(A_log[d * 16 + s]) * 1.44269504f;
  float h = HIN[((size_t)(c * B_SZ + b) * DINNER + d) * 16 + s];
#pragma unroll 4
  for (int l = 0; l < TCHUNK; l++) {
    float dtv = dts[l][dl];
    float a = __builtin_amdgcn_exp2f(dtv * a2);
    h = a * h + dtv * xcs[l][dl] * Bsh[l][s];
    float pp = h * Csh[l][s];
    pp += __shfl_xor(pp, 1);
    pp += __shfl_xor(pp, 2);
    pp += __shfl_xor(pp, 4);
    pp += __shfl_xor(pp, 8);
    if (s == 0) ys[l][dl] = pp;
  }
  __syncthreads();
#pragma unroll
  for (int i = 0; i < 4; i++) {
    int idx = tid + i * 256;
    int li = idx >> 4, di = idx & 15;
    size_t row = (size_t)(b * L_SEQ + l0 + li);
    int gd = db + di;
    float zv = xz[row * 3072 + DINNER + gd];
    float yv = ys[li][di] + xcs[li][di] * Dp[gd];
    ybf[row * DINNER + gd] = f2bf(yv * zv * sigm(zv));
  }
}

// -------------------------------------------------------------- launcher ----
extern "C" void kernel_launch(void* const* d_in, const int* in_sizes, int n_in,
                              void* d_out, int out_size, void* d_ws, size_t ws_size,
                              hipStream_t stream) {
  const float* x    = (const float*)d_in[0];
  const float* w1   = (const float*)d_in[1];
  const float* cw   = (const float*)d_in[2];
  const float* cb   = (const float*)d_in[3];
  const float* alog = (const float*)d_in[4];
  const float* Dp   = (const float*)d_in[5];
  const float* w2   = (const float*)d_in[6];
  const float* dtw  = (const float*)d_in[7];
  const float* dtb  = (const float*)d_in[8];
  const float* w3   = (const float*)d_in[9];
  float* out = (float*)d_out;
  char* ws = (char*)d_ws;

  size_t off = 0;
  auto alloc = [&](size_t bytes) { size_t o = off; off += (bytes + 255) & ~(size_t)255; return o; };
  float*          xz    = (float*)(ws + alloc((size_t)M_ROWS * 3072 * 4));   // 50.3 MB
  float*          xdbl  = (float*)(ws + alloc((size_t)M_ROWS * 128 * 4));    // 2.1 MB
  float*          dtf   = (float*)(ws + alloc((size_t)M_ROWS * DINNER * 4)); // 25.2 MB
  unsigned short* xbf   = (unsigned short*)(ws + alloc((size_t)M_ROWS * DMODEL * 2));
  unsigned short* w1bf  = (unsigned short*)(ws + alloc((size_t)2 * DINNER * DMODEL * 2));
  unsigned short* w2bf  = (unsigned short*)(ws + alloc((size_t)128 * DINNER * 2));
  unsigned short* w3bf  = (unsigned short*)(ws + alloc((size_t)DMODEL * DINNER * 2));
  unsigned short* dtlbf = (unsigned short*)(ws + alloc((size_t)M_ROWS * 64 * 2));
  unsigned short* dtwbf = (unsigned short*)(ws + alloc((size_t)DINNER * 64 * 2));
  unsigned short* xcbf  = (unsigned short*)(ws + alloc((size_t)M_ROWS * DINNER * 2));
  unsigned short* ybf   = (unsigned short*)(ws + alloc((size_t)M_ROWS * DINNER * 2));
  float*          Pbuf  = (float*)(ws + alloc((size_t)NCHUNK * B_SZ * DINNER * 16 * 4));
  float*          HLbuf = (float*)(ws + alloc((size_t)NCHUNK * B_SZ * DINNER * 16 * 4));
  float*          HINb  = (float*)(ws + alloc((size_t)NCHUNK * B_SZ * DINNER * 16 * 4));

  // 1. cast inputs/weights to bf16 (with padding for W2 rows / dtw cols)
  cast_all_kernel<<<27264, 256, 0, stream>>>(x, w1, w2, w3, dtw, xbf, w1bf, w2bf, w3bf, dtwbf);
  // 2. xz = x @ W_in^T  [4096 x 3072], K=768
  gemm_bt<0><<<dim3(32, 24), 256, 0, stream>>>(xbf, w1bf, xz, DMODEL, 3072, nullptr);
  // 3. depthwise conv + SiLU -> xc (bf16)
  conv_silu_kernel<<<24576, 256, 0, stream>>>(xz, cw, cb, xcbf);
  // 4. x_dbl = xc @ W_x^T  [4096 x 128(pad)], K=1536
  gemm_bt<0><<<dim3(32, 1), 256, 0, stream>>>(xcbf, w2bf, xdbl, DINNER, 128, nullptr);
  // 5. dt_low -> bf16 padded K=64
  cast_dtlow_kernel<<<1024, 256, 0, stream>>>(xdbl, dtlbf);
  // 6. dt = softplus(dt_low @ W_dt^T + b)  [4096 x 1536], K=64
  gemm_bt<1><<<dim3(32, 12), 256, 0, stream>>>(dtlbf, dtwbf, dtf, 64, DINNER, dtb);
  // 7-9. chunked selective scan + fused epilogue -> ybf
  scan_phase1<<<dim3(96, 2, 32), 256, 0, stream>>>(dtf, xcbf, xdbl, alog, Pbuf, HLbuf);
  scan_phase2<<<192, 256, 0, stream>>>(Pbuf, HLbuf, HINb);
  scan_phase3<<<dim3(96, 2, 32), 256, 0, stream>>>(dtf, xcbf, xdbl, alog, HINb, xz, Dp, ybf);
  // 10. out = y @ W_out^T  [4096 x 768], K=1536
  gemm_bt<0><<<dim3(32, 6), 256, 0, stream>>>(ybf, w3bf, out, DINNER, 768, nullptr);
}

// Round 2
// 337.314 us; speedup vs baseline: 1.1535x; 1.1535x over previous
//
#include <hip/hip_runtime.h>
#include <stdint.h>

#define B_SZ    2
#define L_SEQ   2048
#define DMODEL  768
#define DSTATE  16
#define DINNER  1536
#define DTRANK  48
#define M_ROWS  4096      // B*L
#define NCHUNK  32
#define TCHUNK  64
#define PADL    68        // LDS row stride in floats: 272 B, 16B-aligned, 2-way bank alias (free)

typedef __attribute__((ext_vector_type(8))) short bf16x8;
typedef __attribute__((ext_vector_type(4))) float f32x4;
typedef __attribute__((ext_vector_type(4))) unsigned int u32x4;

__device__ __forceinline__ unsigned short f2bf(float f) {
  unsigned int u = __float_as_uint(f);
  u += 0x7FFFu + ((u >> 16) & 1u);          // RNE
  return (unsigned short)(u >> 16);
}
__device__ __forceinline__ float bf2f(unsigned short h) {
  return __uint_as_float(((unsigned int)h) << 16);
}
__device__ __forceinline__ float fexp(float x) {   // e^x via v_exp_f32
  return __builtin_amdgcn_exp2f(x * 1.44269504088896340736f);
}
__device__ __forceinline__ float sigm(float x) {
  return 1.0f / (1.0f + fexp(-x));
}

// DPP cross-lane add on the VALU pipe (not LDS). Sums within rows of 16 lanes.
template <int CTRL>
__device__ __forceinline__ float dpp_add(float v) {
  int x = __builtin_amdgcn_update_dpp(0, __float_as_int(v), CTRL, 0xF, 0xF, true);
  return v + __int_as_float(x);
}
__device__ __forceinline__ float row16_sum(float v) {
  v = dpp_add<0xB1>(v);   // quad_perm [1,0,3,2]  : xor 1
  v = dpp_add<0x4E>(v);   // quad_perm [2,3,0,1]  : xor 2
  v = dpp_add<0x124>(v);  // row_ror:4
  v = dpp_add<0x128>(v);  // row_ror:8
  return v;               // all 16 lanes hold the row sum
}

// ---------------------------------------------------------------- casts ----
__global__ void cast_all_kernel(const float* __restrict__ x, const float* __restrict__ w1,
                                const float* __restrict__ w2, const float* __restrict__ w3,
                                const float* __restrict__ dtw,
                                unsigned short* __restrict__ xbf, unsigned short* __restrict__ w1bf,
                                unsigned short* __restrict__ w2bf, unsigned short* __restrict__ w3bf,
                                unsigned short* __restrict__ dtwbf) {
  int i = blockIdx.x * 256 + threadIdx.x;
  const int n_x = M_ROWS * DMODEL;          // 3145728
  const int n_w1 = 2 * DINNER * DMODEL;     // 2359296
  const int n_w3 = DMODEL * DINNER;         // 1179648
  const int n_w2 = 128 * DINNER;            // 196608 (rows padded 80->128)
  const int n_dtw = DINNER * 64;            // 98304  (cols padded 48->64)
  if (i < n_x)  { xbf[i] = f2bf(x[i]); return; }  i -= n_x;
  if (i < n_w1) { w1bf[i] = f2bf(w1[i]); return; } i -= n_w1;
  if (i < n_w3) { w3bf[i] = f2bf(w3[i]); return; } i -= n_w3;
  if (i < n_w2) {
    int row = i / DINNER, col = i - row * DINNER;
    w2bf[i] = (row < (DTRANK + 2 * DSTATE)) ? f2bf(w2[row * DINNER + col]) : (unsigned short)0;
    return;
  }
  i -= n_w2;
  if (i < n_dtw) {
    int row = i >> 6, col = i & 63;
    dtwbf[i] = (col < DTRANK) ? f2bf(dtw[row * DTRANK + col]) : (unsigned short)0;
  }
}

__global__ void cast_dtlow_kernel(const float* __restrict__ xdbl, unsigned short* __restrict__ out) {
  int i = blockIdx.x * 256 + threadIdx.x;   // 4096*64
  int row = i >> 6, col = i & 63;
  out[i] = (col < DTRANK) ? f2bf(xdbl[row * 128 + col]) : (unsigned short)0;
}

// --------------------------------------------------- bf16 MFMA GEMM (B^T) ----
template <int EPI>
__global__ __launch_bounds__(256, 2) void gemm_bt(
    const unsigned short* __restrict__ A, const unsigned short* __restrict__ Bt,
    float* __restrict__ C, int K, int ldc, const float* __restrict__ bias) {
  __shared__ unsigned short As[128 * 40];
  __shared__ unsigned short Bs[128 * 40];
  const int tid = threadIdx.x;
  const int m0 = blockIdx.x * 128;
  const int n0 = blockIdx.y * 128;
  const int lane = tid & 63;
  const int wave = tid >> 6;
  const int wr = (wave >> 1) * 64, wc = (wave & 1) * 64;
  const int lm = lane & 15, q = lane >> 4;
  const int r = tid >> 2, sg = (tid & 3) * 8;       // staging: row, k-seg(elems)

  f32x4 acc[4][4] = {};

  for (int k0 = 0; k0 < K; k0 += 32) {
    u32x4 a0 = *(const u32x4*)(A + (size_t)(m0 + r) * K + k0 + sg);
    u32x4 a1 = *(const u32x4*)(A + (size_t)(m0 + r + 64) * K + k0 + sg);
    u32x4 b0 = *(const u32x4*)(Bt + (size_t)(n0 + r) * K + k0 + sg);
    u32x4 b1 = *(const u32x4*)(Bt + (size_t)(n0 + r + 64) * K + k0 + sg);
    __syncthreads();
    *(u32x4*)&As[r * 40 + sg] = a0;
    *(u32x4*)&As[(r + 64) * 40 + sg] = a1;
    *(u32x4*)&Bs[r * 40 + sg] = b0;
    *(u32x4*)&Bs[(r + 64) * 40 + sg] = b1;
    __syncthreads();
    bf16x8 af[4], bq[4];
#pragma unroll
    for (int mt = 0; mt < 4; mt++)
      af[mt] = *(const bf16x8*)&As[(wr + mt * 16 + lm) * 40 + q * 8];
#pragma unroll
    for (int nt = 0; nt < 4; nt++)
      bq[nt] = *(const bf16x8*)&Bs[(wc + nt * 16 + lm) * 40 + q * 8];
#pragma unroll
    for (int mt = 0; mt < 4; mt++)
#pragma unroll
      for (int nt = 0; nt < 4; nt++)
        acc[mt][nt] = __builtin_amdgcn_mfma_f32_16x16x32_bf16(af[mt], bq[nt], acc[mt][nt], 0, 0, 0);
  }

#pragma unroll
  for (int mt = 0; mt < 4; mt++) {
    int row0 = m0 + wr + mt * 16 + q * 4;
#pragma unroll
    for (int nt = 0; nt < 4; nt++) {
      int col = n0 + wc + nt * 16 + lm;
      float bs = 0.f;
      if (EPI == 1) bs = bias[col];
#pragma unroll
      for (int i = 0; i < 4; i++) {
        float v = acc[mt][nt][i];
        if (EPI == 1) {                      // softplus(v + b), stable
          v += bs;
          v = (v > 15.f) ? v : log1pf(fexp(v));
        }
        C[(size_t)(row0 + i) * ldc + col] = v;
      }
    }
  }
}

// ------------------------------------------------- depthwise conv + SiLU ----
__global__ void conv_silu_kernel(const float* __restrict__ xz, const float* __restrict__ cw,
                                 const float* __restrict__ cb, unsigned short* __restrict__ xcbf) {
  int idx = blockIdx.x * 256 + threadIdx.x;
  if (idx >= B_SZ * L_SEQ * DINNER) return;
  int d = idx % DINNER;
  int bl = idx / DINNER;          // b*L + l
  int l = bl & (L_SEQ - 1);
  float acc = cb[d];
#pragma unroll
  for (int k = 0; k < 4; k++) {
    int ll = l - 3 + k;
    if (ll >= 0) acc += cw[d * 4 + k] * xz[(size_t)(bl - 3 + k) * 3072 + d];
  }
  xcbf[idx] = f2bf(acc * sigm(acc));
}

// ------------------------------------------------------ chunked SSM scan ----
// Transposed LDS ([d or s][l], stride PADL): ds_read_b128 serves 4 steps.
// lane: s = tid&15 (state), dl = tid>>4 (channel within block's 16).
__global__ __launch_bounds__(256) void scan_phase1(
    const float* __restrict__ dt, const unsigned short* __restrict__ xcbf,
    const float* __restrict__ xdbl, const float* __restrict__ A_log,
    float* __restrict__ P, float* __restrict__ HL) {
  __shared__ float dts[16 * PADL], xcs[16 * PADL], Bsh[16 * PADL];
  const int tid = threadIdx.x;
  const int db = blockIdx.x * 16;
  const int b = blockIdx.y;
  const int c = blockIdx.z;
  const int l0c = c * TCHUNK;
  {                                     // staging: thread (di, lg) -> 4 rows, b128 column write
    const int di = tid & 15, lg = tid >> 4;
    f32x4 dv, xv, bv;
#pragma unroll
    for (int j = 0; j < 4; j++) {
      size_t row = (size_t)(b * L_SEQ + l0c + lg * 4 + j);
      dv[j] = dt[row * DINNER + db + di];
      xv[j] = bf2f(xcbf[row * DINNER + db + di]);
      bv[j] = xdbl[row * 128 + DTRANK + di];
    }
    *(f32x4*)&dts[di * PADL + lg * 4] = dv;
    *(f32x4*)&xcs[di * PADL + lg * 4] = xv;
    *(f32x4*)&Bsh[di * PADL + lg * 4] = bv;
  }
  __syncthreads();
  const int s = tid & 15, dl = tid >> 4;
  const int d = db + dl;
  const float a2 = -fexp(A_log[d * 16 + s]) * 1.44269504f;  // A*log2(e)
  float h = 0.f, sdt = 0.f;
  for (int l0 = 0; l0 < TCHUNK; l0 += 4) {
    f32x4 dtv = *(const f32x4*)&dts[dl * PADL + l0];
    f32x4 xcv = *(const f32x4*)&xcs[dl * PADL + l0];
    f32x4 Bv  = *(const f32x4*)&Bsh[s * PADL + l0];
#pragma unroll
    for (int j = 0; j < 4; j++) {
      float a = __builtin_amdgcn_exp2f(dtv[j] * a2);
      h = a * h + dtv[j] * xcv[j] * Bv[j];
      sdt += dtv[j];
    }
  }
  size_t o = ((size_t)(c * B_SZ + b) * DINNER + d) * 16 + s;
  P[o] = __builtin_amdgcn_exp2f(a2 * sdt);   // prod of a == exp(A * sum dt)
  HL[o] = h;
}

__global__ void scan_phase2(const float* __restrict__ P, const float* __restrict__ HL,
                            float* __restrict__ HIN) {
  int tg = blockIdx.x * 256 + threadIdx.x;  // 49152 total
  int s = tg & 15;
  int rem = tg >> 4;
  int d = rem % DINNER;
  int b = rem / DINNER;
  float h = 0.f;
  for (int c = 0; c < NCHUNK; c++) {
    size_t o = ((size_t)(c * B_SZ + b) * DINNER + d) * 16 + s;
    HIN[o] = h;
    h = P[o] * h + HL[o];
  }
}

__global__ __launch_bounds__(256) void scan_phase3(
    const float* __restrict__ dt, const unsigned short* __restrict__ xcbf,
    const float* __restrict__ xdbl, const float* __restrict__ A_log,
    const float* __restrict__ HIN, const float* __restrict__ xz,
    const float* __restrict__ Dp, unsigned short* __restrict__ ybf) {
  __shared__ float dts[16 * PADL], xcs[16 * PADL], Bsh[16 * PADL], Csh[16 * PADL], ysh[16 * PADL];
  const int tid = threadIdx.x;
  const int db = blockIdx.x * 16;
  const int b = blockIdx.y;
  const int c = blockIdx.z;
  const int l0c = c * TCHUNK;
  const int di = tid & 15, lg = tid >> 4;
  {                                     // staging
    f32x4 dv, xv, bv, cv;
#pragma unroll
    for (int j = 0; j < 4; j++) {
      size_t row = (size_t)(b * L_SEQ + l0c + lg * 4 + j);
      dv[j] = dt[row * DINNER + db + di];
      xv[j] = bf2f(xcbf[row * DINNER + db + di]);
      bv[j] = xdbl[row * 128 + DTRANK + di];
      cv[j] = xdbl[row * 128 + DTRANK + DSTATE + di];
    }
    *(f32x4*)&dts[di * PADL + lg * 4] = dv;
    *(f32x4*)&xcs[di * PADL + lg * 4] = xv;
    *(f32x4*)&Bsh[di * PADL + lg * 4] = bv;
    *(f32x4*)&Csh[di * PADL + lg * 4] = cv;
  }
  __syncthreads();
  const int s = tid & 15, dl = tid >> 4;
  const int d = db + dl;
  const float a2 = -fexp(A_log[d * 16 + s]) * 1.44269504f;
  float h = HIN[((size_t)(c * B_SZ + b) * DINNER + d) * 16 + s];
  for (int l0 = 0; l0 < TCHUNK; l0 += 4) {
    f32x4 dtv = *(const f32x4*)&dts[dl * PADL + l0];
    f32x4 xcv = *(const f32x4*)&xcs[dl * PADL + l0];
    f32x4 Bv  = *(const f32x4*)&Bsh[s * PADL + l0];
    f32x4 Cv  = *(const f32x4*)&Csh[s * PADL + l0];
    f32x4 y4;
#pragma unroll
    for (int j = 0; j < 4; j++) {
      float a = __builtin_amdgcn_exp2f(dtv[j] * a2);
      h = a * h + dtv[j] * xcv[j] * Bv[j];
      y4[j] = row16_sum(h * Cv[j]);        // DPP on VALU pipe, no LDS
    }
    if (s == 0) *(f32x4*)&ysh[dl * PADL + l0] = y4;
  }
  __syncthreads();
#pragma unroll
  for (int i = 0; i < 4; i++) {
    int l = lg + i * 16;
    size_t row = (size_t)(b * L_SEQ + l0c + l);
    int gd = db + di;
    float zv = xz[row * 3072 + DINNER + gd];
    float yv = ysh[di * PADL + l] + xcs[di * PADL + l] * Dp[gd];
    ybf[row * DINNER + gd] = f2bf(yv * zv * sigm(zv));
  }
}

// -------------------------------------------------------------- launcher ----
extern "C" void kernel_launch(void* const* d_in, const int* in_sizes, int n_in,
                              void* d_out, int out_size, void* d_ws, size_t ws_size,
                              hipStream_t stream) {
  const float* x    = (const float*)d_in[0];
  const float* w1   = (const float*)d_in[1];
  const float* cw   = (const float*)d_in[2];
  const float* cb   = (const float*)d_in[3];
  const float* alog = (const float*)d_in[4];
  const float* Dp   = (const float*)d_in[5];
  const float* w2   = (const float*)d_in[6];
  const float* dtw  = (const float*)d_in[7];
  const float* dtb  = (const float*)d_in[8];
  const float* w3   = (const float*)d_in[9];
  float* out = (float*)d_out;
  char* ws = (char*)d_ws;

  size_t off = 0;
  auto alloc = [&](size_t bytes) { size_t o = off; off += (bytes + 255) & ~(size_t)255; return o; };
  float*          xz    = (float*)(ws + alloc((size_t)M_ROWS * 3072 * 4));   // 50.3 MB
  float*          xdbl  = (float*)(ws + alloc((size_t)M_ROWS * 128 * 4));    // 2.1 MB
  float*          dtf   = (float*)(ws + alloc((size_t)M_ROWS * DINNER * 4)); // 25.2 MB
  unsigned short* xbf   = (unsigned short*)(ws + alloc((size_t)M_ROWS * DMODEL * 2));
  unsigned short* w1bf  = (unsigned short*)(ws + alloc((size_t)2 * DINNER * DMODEL * 2));
  unsigned short* w2bf  = (unsigned short*)(ws + alloc((size_t)128 * DINNER * 2));
  unsigned short* w3bf  = (unsigned short*)(ws + alloc((size_t)DMODEL * DINNER * 2));
  unsigned short* dtlbf = (unsigned short*)(ws + alloc((size_t)M_ROWS * 64 * 2));
  unsigned short* dtwbf = (unsigned short*)(ws + alloc((size_t)DINNER * 64 * 2));
  unsigned short* xcbf  = (unsigned short*)(ws + alloc((size_t)M_ROWS * DINNER * 2));
  unsigned short* ybf   = (unsigned short*)(ws + alloc((size_t)M_ROWS * DINNER * 2));
  float*          Pbuf  = (float*)(ws + alloc((size_t)NCHUNK * B_SZ * DINNER * 16 * 4));
  float*          HLbuf = (float*)(ws + alloc((size_t)NCHUNK * B_SZ * DINNER * 16 * 4));
  float*          HINb  = (float*)(ws + alloc((size_t)NCHUNK * B_SZ * DINNER * 16 * 4));

  // 1. cast inputs/weights to bf16 (with padding for W2 rows / dtw cols)
  cast_all_kernel<<<27264, 256, 0, stream>>>(x, w1, w2, w3, dtw, xbf, w1bf, w2bf, w3bf, dtwbf);
  // 2. xz = x @ W_in^T  [4096 x 3072], K=768
  gemm_bt<0><<<dim3(32, 24), 256, 0, stream>>>(xbf, w1bf, xz, DMODEL, 3072, nullptr);
  // 3. depthwise conv + SiLU -> xc (bf16)
  conv_silu_kernel<<<24576, 256, 0, stream>>>(xz, cw, cb, xcbf);
  // 4. x_dbl = xc @ W_x^T  [4096 x 128(pad)], K=1536
  gemm_bt<0><<<dim3(32, 1), 256, 0, stream>>>(xcbf, w2bf, xdbl, DINNER, 128, nullptr);
  // 5. dt_low -> bf16 padded K=64
  cast_dtlow_kernel<<<1024, 256, 0, stream>>>(xdbl, dtlbf);
  // 6. dt = softplus(dt_low @ W_dt^T + b)  [4096 x 1536], K=64
  gemm_bt<1><<<dim3(32, 12), 256, 0, stream>>>(dtlbf, dtwbf, dtf, 64, DINNER, dtb);
  // 7-9. chunked selective scan + fused epilogue -> ybf
  scan_phase1<<<dim3(96, 2, 32), 256, 0, stream>>>(dtf, xcbf, xdbl, alog, Pbuf, HLbuf);
  scan_phase2<<<192, 256, 0, stream>>>(Pbuf, HLbuf, HINb);
  scan_phase3<<<dim3(96, 2, 32), 256, 0, stream>>>(dtf, xcbf, xdbl, alog, HINb, xz, Dp, ybf);
  // 10. out = y @ W_out^T  [4096 x 768], K=1536
  gemm_bt<0><<<dim3(32, 6), 256, 0, stream>>>(ybf, w3bf, out, DINNER, 768, nullptr);
}